// Round 4
// baseline (329.668 us; speedup 1.0000x reference)
//
#include <hip/hip_runtime.h>

// DFAProb: transposed-DFA fuzzy sum-product, semiring='prob'.
// Per row i (B = 2M rows, 8 states):
//   ab = a*b, anb = a*(1-b), na = 1-a
//   unnorm[ns] = s0[(ns-1)&7]*ab + s0[(ns-2)&7]*anb + s0[ns]*na
//   denom = sum(unnorm)  (detached -> forward only)
//   next  = clip(unnorm/denom, 1e-7, 1-1e-7)
//   outputs (concat flat): log(next) [B*8], next [B*8], next[:,7] [B]
// log_s0 input is UNUSED by the reference -> never read (saves 64 MB).
// Memory-bound: ~216 MB total traffic -> ~34 us at 6.3 TB/s.
// R1: nontemporal loads/stores (streaming, no reuse), 2 rows/thread.
// R3: __builtin_nontemporal_* rejects HIP_vector_type (float4 is a class);
//     must use native ext_vector_type vectors.

#define DFA_EPS 1e-7f

typedef float f32x4 __attribute__((ext_vector_type(4)));
typedef float f32x2 __attribute__((ext_vector_type(2)));

__device__ __forceinline__ void dfa_row(const f32x4 lo, const f32x4 hi,
                                        const float av, const float bv,
                                        float* __restrict__ log_out,
                                        float* __restrict__ ns_out,
                                        float* __restrict__ acc_out,
                                        size_t i)
{
    const float ab  = av * bv;
    const float anb = av * (1.0f - bv);
    const float na  = 1.0f - av;

    const float s[8] = {lo.x, lo.y, lo.z, lo.w, hi.x, hi.y, hi.z, hi.w};

    float un[8];
    float denom = 0.0f;
#pragma unroll
    for (int n = 0; n < 8; ++n) {
        un[n] = fmaf(s[(n + 7) & 7], ab,
                fmaf(s[(n + 6) & 7], anb, s[n] * na));
        denom += un[n];
    }

    const float inv = 1.0f / denom;

    float nsv[8], lg[8];
#pragma unroll
    for (int n = 0; n < 8; ++n) {
        float v = un[n] * inv;
        v = fminf(fmaxf(v, DFA_EPS), 1.0f - DFA_EPS);
        nsv[n] = v;
        lg[n] = __logf(v);   // v_log_f32 * ln2 — plenty for 0.215 absmax
    }

    f32x4* lg4 = reinterpret_cast<f32x4*>(log_out + i * 8);
    __builtin_nontemporal_store((f32x4){lg[0], lg[1], lg[2], lg[3]}, lg4 + 0);
    __builtin_nontemporal_store((f32x4){lg[4], lg[5], lg[6], lg[7]}, lg4 + 1);

    f32x4* ns4 = reinterpret_cast<f32x4*>(ns_out + i * 8);
    __builtin_nontemporal_store((f32x4){nsv[0], nsv[1], nsv[2], nsv[3]}, ns4 + 0);
    __builtin_nontemporal_store((f32x4){nsv[4], nsv[5], nsv[6], nsv[7]}, ns4 + 1);

    __builtin_nontemporal_store(nsv[7], acc_out + i);
}

__global__ __launch_bounds__(256) void dfa_prob_kernel(
    const float* __restrict__ s0,
    const float* __restrict__ a_in,
    const float* __restrict__ b_in,
    float* __restrict__ log_out,   // B*8
    float* __restrict__ ns_out,    // B*8
    float* __restrict__ acc_out,   // B
    int Bpairs)                    // B/2 (B even: 2,000,000)
{
    const int stride = gridDim.x * blockDim.x;
    for (int p = blockIdx.x * blockDim.x + threadIdx.x; p < Bpairs; p += stride) {
        const size_t i = (size_t)p * 2;

        // 8 B vector loads of guards for both rows
        const f32x2 a2 = __builtin_nontemporal_load(
            reinterpret_cast<const f32x2*>(a_in + i));
        const f32x2 b2 = __builtin_nontemporal_load(
            reinterpret_cast<const f32x2*>(b_in + i));

        // 64 B of s0 for the two rows (4 x 16 B, issued back-to-back)
        const f32x4* s4 = reinterpret_cast<const f32x4*>(s0 + i * 8);
        const f32x4 r0lo = __builtin_nontemporal_load(s4 + 0);
        const f32x4 r0hi = __builtin_nontemporal_load(s4 + 1);
        const f32x4 r1lo = __builtin_nontemporal_load(s4 + 2);
        const f32x4 r1hi = __builtin_nontemporal_load(s4 + 3);

        dfa_row(r0lo, r0hi, a2.x, b2.x, log_out, ns_out, acc_out, i);
        dfa_row(r1lo, r1hi, a2.y, b2.y, log_out, ns_out, acc_out, i + 1);
    }
}

extern "C" void kernel_launch(void* const* d_in, const int* in_sizes, int n_in,
                              void* d_out, int out_size, void* d_ws, size_t ws_size,
                              hipStream_t stream) {
    // Inputs (setup_inputs order): log_s0 [B*8] (UNUSED), s0 [B*8], a [B], b [B]
    const float* s0 = (const float*)d_in[1];
    const float* a  = (const float*)d_in[2];
    const float* b  = (const float*)d_in[3];
    const int B = in_sizes[2];
    const int Bpairs = B / 2;   // B = 2,000,000 is even

    float* out = (float*)d_out;
    float* log_out = out;                         // [B*8]
    float* ns_out  = out + (size_t)B * 8;         // [B*8]
    float* acc_out = out + (size_t)B * 16;        // [B]

    const int block = 256;
    int grid = (Bpairs + block - 1) / block;
    if (grid > 2048) grid = 2048;                 // grid-stride the rest (G11)
    dfa_prob_kernel<<<grid, block, 0, stream>>>(s0, a, b, log_out, ns_out, acc_out, Bpairs);
}

// Round 7
// 234.452 us; speedup vs baseline: 1.4061x; 1.4061x over previous
//
#include <hip/hip_runtime.h>

// DFAProb: transposed-DFA fuzzy sum-product, semiring='prob'.
// Per row i (B = 2M rows, 8 states):
//   ab = a*b, anb = a*(1-b), na = 1-a
//   unnorm[ns] = s0[(ns-1)&7]*ab + s0[(ns-2)&7]*anb + s0[ns]*na
//   denom = sum(unnorm)  (detached -> forward only)
//   next  = clip(unnorm/denom, 1e-7, 1-1e-7)
//   outputs (concat flat): log(next) [B*8], next [B*8], next[:,7] [B]
// log_s0 input is UNUSED by the reference -> never read (saves 64 MB).
// Traffic: ~43 MB HBM fetch (inputs L2/L3-resident from harness restore)
//          + 136 MB write -> write-bound, ~30-40 us floor.
// R4 post-mortem: nontemporal stores 2x'd WRITE_SIZE (268 MB vs 136) --
//   nt bypasses L2 write-combining and the 64B-lane-stride 16B stores can't
//   merge. REVERT to plain stores + 1 row/thread (contiguous 32B/thread).
// R5/R6: broker capacity timeouts -> resubmit, no measurement.

#define DFA_EPS 1e-7f

typedef float f32x4 __attribute__((ext_vector_type(4)));

__global__ __launch_bounds__(256) void dfa_prob_kernel(
    const float* __restrict__ s0,
    const float* __restrict__ a_in,
    const float* __restrict__ b_in,
    float* __restrict__ log_out,   // B*8
    float* __restrict__ ns_out,    // B*8
    float* __restrict__ acc_out,   // B
    int B)
{
    const int stride = gridDim.x * blockDim.x;
    for (int i = blockIdx.x * blockDim.x + threadIdx.x; i < B; i += stride) {
        const float av = a_in[i];
        const float bv = b_in[i];
        const float ab  = av * bv;
        const float anb = av * (1.0f - bv);
        const float na  = 1.0f - av;

        // 32 B vector load of the row (2 x dwordx4)
        const f32x4* s4 = reinterpret_cast<const f32x4*>(s0 + (size_t)i * 8);
        const f32x4 lo = s4[0];
        const f32x4 hi = s4[1];
        const float s[8] = {lo.x, lo.y, lo.z, lo.w, hi.x, hi.y, hi.z, hi.w};

        float un[8];
        float denom = 0.0f;
#pragma unroll
        for (int n = 0; n < 8; ++n) {
            un[n] = fmaf(s[(n + 7) & 7], ab,
                    fmaf(s[(n + 6) & 7], anb, s[n] * na));
            denom += un[n];
        }

        const float inv = 1.0f / denom;

        float nsv[8], lg[8];
#pragma unroll
        for (int n = 0; n < 8; ++n) {
            float v = un[n] * inv;
            v = fminf(fmaxf(v, DFA_EPS), 1.0f - DFA_EPS);
            nsv[n] = v;
            lg[n] = __logf(v);   // v_log_f32 * ln2 — plenty for 0.215 absmax
        }

        f32x4* lg4 = reinterpret_cast<f32x4*>(log_out + (size_t)i * 8);
        lg4[0] = (f32x4){lg[0], lg[1], lg[2], lg[3]};
        lg4[1] = (f32x4){lg[4], lg[5], lg[6], lg[7]};

        f32x4* ns4 = reinterpret_cast<f32x4*>(ns_out + (size_t)i * 8);
        ns4[0] = (f32x4){nsv[0], nsv[1], nsv[2], nsv[3]};
        ns4[1] = (f32x4){nsv[4], nsv[5], nsv[6], nsv[7]};

        acc_out[i] = nsv[7];   // 4B-stride across lanes: fully coalesced
    }
}

extern "C" void kernel_launch(void* const* d_in, const int* in_sizes, int n_in,
                              void* d_out, int out_size, void* d_ws, size_t ws_size,
                              hipStream_t stream) {
    // Inputs (setup_inputs order): log_s0 [B*8] (UNUSED), s0 [B*8], a [B], b [B]
    const float* s0 = (const float*)d_in[1];
    const float* a  = (const float*)d_in[2];
    const float* b  = (const float*)d_in[3];
    const int B = in_sizes[2];

    float* out = (float*)d_out;
    float* log_out = out;                         // [B*8]
    float* ns_out  = out + (size_t)B * 8;         // [B*8]
    float* acc_out = out + (size_t)B * 16;        // [B]

    const int block = 256;
    int grid = (B + block - 1) / block;
    if (grid > 2048) grid = 2048;                 // grid-stride the rest (G11)
    dfa_prob_kernel<<<grid, block, 0, stream>>>(s0, a, b, log_out, ns_out, acc_out, B);
}

// Round 8
// 234.112 us; speedup vs baseline: 1.4082x; 1.0014x over previous
//
#include <hip/hip_runtime.h>

// DFAProb: transposed-DFA fuzzy sum-product, semiring='prob'.
// Per row i (B = 2M rows, 8 states):
//   ab = a*b, anb = a*(1-b), na = 1-a
//   unnorm[ns] = s0[(ns-1)&7]*ab + s0[(ns-2)&7]*anb + s0[ns]*na
//   denom = sum(unnorm)  (detached -> forward only)
//   next  = clip(unnorm/denom, 1e-7, 1-1e-7)
//   outputs (concat flat): log(next) [B*8], next [B*8], next[:,7] [B]
// log_s0 input is UNUSED by the reference -> never read (saves 64 MB).
// Harness floor ~178 us (poison fills + restore, measured R4 vs R7);
// kernel ~56 us vs ~30 us traffic ideal -> latency-bound (R4: VALU 5.5%,
// occ 50%, HBM 26%), not BW-bound.
// R7: exact grid, 1 row/thread, NO grid-stride loop -> max TLP, all loads
//     issue at wave start (fill kernel hits 6.6 TB/s with this shape).

#define DFA_EPS 1e-7f

typedef float f32x4 __attribute__((ext_vector_type(4)));

__global__ __launch_bounds__(256) void dfa_prob_kernel(
    const float* __restrict__ s0,
    const float* __restrict__ a_in,
    const float* __restrict__ b_in,
    float* __restrict__ log_out,   // B*8
    float* __restrict__ ns_out,    // B*8
    float* __restrict__ acc_out,   // B
    int B)
{
    const int i = blockIdx.x * blockDim.x + threadIdx.x;
    if (i >= B) return;

    const float av = a_in[i];
    const float bv = b_in[i];
    const float ab  = av * bv;
    const float anb = av * (1.0f - bv);
    const float na  = 1.0f - av;

    // 32 B vector load of the row (2 x dwordx4)
    const f32x4* s4 = reinterpret_cast<const f32x4*>(s0 + (size_t)i * 8);
    const f32x4 lo = s4[0];
    const f32x4 hi = s4[1];
    const float s[8] = {lo.x, lo.y, lo.z, lo.w, hi.x, hi.y, hi.z, hi.w};

    float un[8];
    float denom = 0.0f;
#pragma unroll
    for (int n = 0; n < 8; ++n) {
        un[n] = fmaf(s[(n + 7) & 7], ab,
                fmaf(s[(n + 6) & 7], anb, s[n] * na));
        denom += un[n];
    }

    const float inv = 1.0f / denom;

    float nsv[8], lg[8];
#pragma unroll
    for (int n = 0; n < 8; ++n) {
        float v = un[n] * inv;
        v = fminf(fmaxf(v, DFA_EPS), 1.0f - DFA_EPS);
        nsv[n] = v;
        lg[n] = __logf(v);   // v_log_f32 * ln2 — plenty for 0.215 absmax
    }

    f32x4* lg4 = reinterpret_cast<f32x4*>(log_out + (size_t)i * 8);
    lg4[0] = (f32x4){lg[0], lg[1], lg[2], lg[3]};
    lg4[1] = (f32x4){lg[4], lg[5], lg[6], lg[7]};

    f32x4* ns4 = reinterpret_cast<f32x4*>(ns_out + (size_t)i * 8);
    ns4[0] = (f32x4){nsv[0], nsv[1], nsv[2], nsv[3]};
    ns4[1] = (f32x4){nsv[4], nsv[5], nsv[6], nsv[7]};

    acc_out[i] = nsv[7];   // 4B-stride across lanes: fully coalesced
}

extern "C" void kernel_launch(void* const* d_in, const int* in_sizes, int n_in,
                              void* d_out, int out_size, void* d_ws, size_t ws_size,
                              hipStream_t stream) {
    // Inputs (setup_inputs order): log_s0 [B*8] (UNUSED), s0 [B*8], a [B], b [B]
    const float* s0 = (const float*)d_in[1];
    const float* a  = (const float*)d_in[2];
    const float* b  = (const float*)d_in[3];
    const int B = in_sizes[2];

    float* out = (float*)d_out;
    float* log_out = out;                         // [B*8]
    float* ns_out  = out + (size_t)B * 8;         // [B*8]
    float* acc_out = out + (size_t)B * 16;        // [B]

    const int block = 256;
    const int grid = (B + block - 1) / block;     // exact: one row per thread
    dfa_prob_kernel<<<grid, block, 0, stream>>>(s0, a, b, log_out, ns_out, acc_out, B);
}